// Round 4
// baseline (243.378 us; speedup 1.0000x reference)
//
#include <hip/hip_runtime.h>
#include <hip/hip_bf16.h>

namespace {
constexpr int kB = 2, kW = 5, kS = 5, kQ = 75, kC = 64, kHW = 441;
constexpr int kNP = 448;   // support positions padded (14 * 32)
constexpr int kMP = 448;   // query positions padded (14 col-tiles)
constexpr int kNT = 14;    // 32-row tiles
constexpr int kCHUNK = 112;
constexpr int kLDT = 65;   // odd stride -> conflict-free transpose scratch
constexpr int kSupUnits = kB * kW * 4;            // 40
constexpr int kUnits = kSupUnits + kB * kQ * 4;   // 640
constexpr int kTiles = kB * kQ * kW;              // 750
constexpr int kGrid = 512;                        // == guaranteed 2 blocks/CU * 256 CU

typedef short bf16x8 __attribute__((ext_vector_type(8)));
typedef float f32x16 __attribute__((ext_vector_type(16)));
}

__device__ __forceinline__ float max16_v(const f32x16& a) {
  float m0 = fmaxf(fmaxf(a[0], a[1]), a[2]);
  float m1 = fmaxf(fmaxf(a[3], a[4]), a[5]);
  float m2 = fmaxf(fmaxf(a[6], a[7]), a[8]);
  float m3 = fmaxf(fmaxf(a[9], a[10]), a[11]);
  float m4 = fmaxf(fmaxf(a[12], a[13]), a[14]);
  return fmaxf(fmaxf(fmaxf(m0, m1), m2), fmaxf(fmaxf(m3, m4), a[15]));
}
__device__ __forceinline__ float max12_v(const f32x16& a) {
  float m0 = fmaxf(fmaxf(a[0], a[1]), a[2]);
  float m1 = fmaxf(fmaxf(a[3], a[4]), a[5]);
  float m2 = fmaxf(fmaxf(a[6], a[7]), a[8]);
  float m3 = fmaxf(fmaxf(a[9], a[10]), a[11]);
  return fmaxf(fmaxf(m0, m1), fmaxf(m2, m3));
}

// ---- Phase A unit: shot-mean + L2-norm + transpose -> bf16 position-major ----
__device__ void prep_unit(int u, int tid, const float* __restrict__ sup,
                          const float* __restrict__ qry,
                          unsigned short* __restrict__ snT,
                          unsigned short* __restrict__ qnT,
                          float* img_t, float* inv) {
  int m0, mcnt;
  unsigned short* dst;
  if (u < kSupUnits) {
    int bw = u >> 2, chunk = u & 3;
    m0 = chunk * kCHUNK;
    mcnt = min(kCHUNK, kHW - m0);
    const float* base = sup + (size_t)bw * kS * kC * kHW;
    for (int i = tid; i < kC * kCHUNK; i += 256) {
      int c = i / kCHUNK, mm = i % kCHUNK;
      float v = 0.f;
      if (mm < mcnt) {
        const float* p = base + (size_t)c * kHW + m0 + mm;
        float s = 0.f;
#pragma unroll
        for (int k = 0; k < kS; ++k) s += p[(size_t)k * kC * kHW];
        v = s * (1.f / kS);
      }
      img_t[mm * kLDT + c] = v;
    }
    dst = snT + (size_t)bw * kNP * kC;
  } else {
    int qb = u - kSupUnits;
    int bq = qb >> 2, chunk = qb & 3;
    m0 = chunk * kCHUNK;
    mcnt = min(kCHUNK, kHW - m0);
    const float* base = qry + (size_t)bq * kC * kHW;
    for (int i = tid; i < kC * kCHUNK; i += 256) {
      int c = i / kCHUNK, mm = i % kCHUNK;
      img_t[mm * kLDT + c] = (mm < mcnt) ? base[(size_t)c * kHW + m0 + mm] : 0.f;
    }
    dst = qnT + (size_t)bq * kMP * kC;
  }
  __syncthreads();

  if (tid < kCHUNK) {
    float ss = 0.f;
#pragma unroll
    for (int c = 0; c < kC; ++c) { float v = img_t[tid * kLDT + c]; ss += v * v; }
    inv[tid] = 1.f / fmaxf(sqrtf(ss), 1e-12f);
  }
  __syncthreads();

  for (int i8 = tid; i8 < kCHUNK * 8; i8 += 256) {
    int m = i8 >> 3, c8 = (i8 & 7) * 8;
    float sc = inv[m];
    union { unsigned short u16[8]; uint4 v; } pk;
#pragma unroll
    for (int j = 0; j < 8; ++j) {
      __hip_bfloat16 o = __float2bfloat16(img_t[m * kLDT + c8 + j] * sc);
      pk.u16[j] = *reinterpret_cast<unsigned short*>(&o);
    }
    *reinterpret_cast<uint4*>(dst + ((size_t)(m0 + m) * kC + c8)) = pk.v;
  }
}

// ---- Phase C tile: sim = Sn(448x64) x Qn^T(64x448), max over n, sum over m ----
__device__ void tile_compute(int idx, int tid, const unsigned short* __restrict__ qnT,
                             const unsigned short* __restrict__ snT,
                             float* __restrict__ out,
                             unsigned short* As, float* part) {
  const int w = idx % kW;
  const int bq = idx / kW;
  const int b = bq / kQ;

  // stage support tile; swizzle 16B chunks: chunk(n,k16) -> n*8 + (k16 ^ (n&7))
  {
    const uint4* src = reinterpret_cast<const uint4*>(snT + (size_t)(b * kW + w) * kNP * kC);
    uint4* dst = reinterpret_cast<uint4*>(As);
#pragma unroll
    for (int it = 0; it < (kNP * kC / 8) / 256; ++it) {  // 14 iters
      int i = it * 256 + tid;
      int n = i >> 3, k16 = i & 7;
      dst[n * 8 + (k16 ^ (n & 7))] = src[i];
    }
  }

  const int lane = tid & 63;
  const int lh = lane >> 5;
  const int lm = lane & 31;
  const int wid = tid >> 6;
  const int ct0 = (wid < 2) ? wid * 4 : 8 + (wid - 2) * 3;  // col-tiles {4,4,3,3}
  const int nct = (wid < 2) ? 4 : 3;

  bf16x8 bf[4][4];
  const unsigned short* qb = qnT + (size_t)bq * kMP * kC;
#pragma unroll
  for (int ct = 0; ct < 4; ++ct) {
    if (ct < nct) {
      int m = (ct0 + ct) * 32 + lm;
#pragma unroll
      for (int kk = 0; kk < 4; ++kk)
        bf[ct][kk] = *reinterpret_cast<const bf16x8*>(qb + (size_t)m * kC + kk * 16 + lh * 8);
    }
  }
  __syncthreads();

  f32x16 z;
#pragma unroll
  for (int r = 0; r < 16; ++r) z[r] = 0.f;
  float rm[4] = {-INFINITY, -INFINITY, -INFINITY, -INFINITY};

  for (int nt = 0; nt < kNT; ++nt) {
    bf16x8 af[4];
    int n = nt * 32 + lm;
#pragma unroll
    for (int kk = 0; kk < 4; ++kk) {
      int k16 = kk * 2 + lh;
      af[kk] = *reinterpret_cast<const bf16x8*>(As + ((size_t)(n * 8 + (k16 ^ (n & 7))) << 3));
    }
    if (nt < kNT - 1) {
#pragma unroll
      for (int ct = 0; ct < 4; ++ct) {
        if (ct < nct) {
          f32x16 acc = z;
#pragma unroll
          for (int kk = 0; kk < 4; ++kk)
            acc = __builtin_amdgcn_mfma_f32_32x32x16_bf16(af[kk], bf[ct][kk], acc, 0, 0, 0);
          rm[ct] = fmaxf(rm[ct], max16_v(acc));
        }
      }
    } else {
      // tail rows n=416..447; valid n<441 -> local row <= 24.
      // row = (r&3)+8*(r>>2)+4*lh: lh0 invalid regs {13,14,15}, lh1 invalid {12..15}
#pragma unroll
      for (int ct = 0; ct < 4; ++ct) {
        if (ct < nct) {
          f32x16 acc = z;
#pragma unroll
          for (int kk = 0; kk < 4; ++kk)
            acc = __builtin_amdgcn_mfma_f32_32x32x16_bf16(af[kk], bf[ct][kk], acc, 0, 0, 0);
          float t = max12_v(acc);
          if (lh == 0) t = fmaxf(t, acc[12]);  // row 24 still valid
          rm[ct] = fmaxf(rm[ct], t);
        }
      }
    }
  }

  float s = 0.f;
#pragma unroll
  for (int ct = 0; ct < 4; ++ct) {
    if (ct < nct) s += fmaxf(rm[ct], __shfl_xor(rm[ct], 32, 64));
  }
#pragma unroll
  for (int off = 1; off < 32; off <<= 1) s += __shfl_xor(s, off, 64);

  if (lane == 0) part[wid] = s;
  __syncthreads();
  if (tid == 0) out[idx] = part[0] + part[1] + part[2] + part[3];
}

// ---- single regular kernel with home-grown grid barrier ----
// grid=512, __launch_bounds__(256,2): VGPR<=256 and LDS 57.4KB*2<=160KB guarantee
// 2 blocks/CU co-residency -> all 512 blocks resident -> spin barrier cannot deadlock.
__global__ __launch_bounds__(256, 2) void dn4_one_k(const float* __restrict__ sup,
                                                    const float* __restrict__ qry,
                                                    unsigned short* __restrict__ snT,
                                                    unsigned short* __restrict__ qnT,
                                                    float* __restrict__ out,
                                                    unsigned int* __restrict__ ctr) {
  __shared__ __align__(16) char smem[kNP * kC * 2 + 16];  // 57360 B
  const int tid = threadIdx.x;
  const int bid = blockIdx.x;

  // ---------------- Phase A: prep (640 units over 512 blocks) ----------------
  float* img_t = reinterpret_cast<float*>(smem);
  float* inv = reinterpret_cast<float*>(smem + kCHUNK * kLDT * 4);
  for (int u = bid; u < kUnits; u += kGrid) {
    prep_unit(u, tid, sup, qry, snT, qnT, img_t, inv);
    __syncthreads();
  }

  // ---------------- grid barrier (arrive + spin), agent scope ----------------
  __threadfence();   // release this block's ws writes to agent scope
  __syncthreads();
  if (tid == 0) {
    __hip_atomic_fetch_add(ctr, 1u, __ATOMIC_ACQ_REL, __HIP_MEMORY_SCOPE_AGENT);
    while (__hip_atomic_load(ctr, __ATOMIC_ACQUIRE, __HIP_MEMORY_SCOPE_AGENT) < (unsigned)kGrid)
      __builtin_amdgcn_s_sleep(2);
  }
  __syncthreads();
  __threadfence();   // acquire: invalidate stale cached ws lines

  // ---------------- Phase C: tiles (750 over 512 blocks) ----------------
  unsigned short* As = reinterpret_cast<unsigned short*>(smem);
  float* part = reinterpret_cast<float*>(smem + kNP * kC * 2);
  for (int t = bid; t < kTiles; t += kGrid) {
    __syncthreads();
    tile_compute(t, tid, qnT, snT, out, As, part);
  }
}

extern "C" void kernel_launch(void* const* d_in, const int* in_sizes, int n_in,
                              void* d_out, int out_size, void* d_ws, size_t ws_size,
                              hipStream_t stream) {
  const float* sup = (const float*)d_in[0];
  const float* qry = (const float*)d_in[2];
  float* out = (float*)d_out;

  unsigned short* snT = (unsigned short*)d_ws;                 // 573,440 B
  unsigned short* qnT = snT + (size_t)kB * kW * kNP * kC;      // 8,601,600 B
  unsigned int* ctr = (unsigned int*)((char*)d_ws + (32u << 20));  // ws is 256 MiB

  hipMemsetAsync(ctr, 0, sizeof(unsigned int), stream);
  dn4_one_k<<<kGrid, 256, 0, stream>>>(sup, qry, snT, qnT, out, ctr);
}